// Round 1
// baseline (148.046 us; speedup 1.0000x reference)
//
#include <hip/hip_runtime.h>

// Loss = mean(0.5*(o-t)^2 * ef(t)) over N = 64*1*512*512 fp32 elements.
// ef(t) = (BETA-c)*(1 - gamma_pdf(t)/FX_MAX) + c,  c = 1/(Y_MAX-Y_MIN)
// Folded: ef(t) = BETA - exp((A-1)*ln(x) - x + BIAS),  x = (t - LOC)/SCALE
//   BIAS = ln((BETA-c)/FX_MAX) - ln(SCALE*Gamma(A)) = -56.8416699
//   (lnGamma(0.06444291424643259) = 2.7080909 via series; verified:
//    exponent at t=0 -> 1.6075717 ~= ln(BETA-c)=1.6075708, i.e. ef(0)=c.)
// For t >= 2^-23 the exp underflows to ~0 -> ef ~= BETA = 5.

#define NBLOCKS 2048
#define NTHREADS 256

__device__ __forceinline__ float ef_term(float o, float y) {
    constexpr float A_M1      = -0.93555708575356741f;  // EST_A - 1
    constexpr float NEG_LOC   =  1.1328205299926424e-27f;
    constexpr float INV_SCALE =  0.65034886603218541f;  // 1/1.5376362609160314
    constexpr float BIAS      = -56.8416699f;
    constexpr float BETA      =  5.0f;

    float x  = (y + NEG_LOC) * INV_SCALE;           // always > 0 (fp32 normal)
    float ex = __expf(fmaf(A_M1, __logf(x), BIAS - x));
    float ef = BETA - ex;                            // == c when y == 0
    float d  = o - y;
    return 0.5f * d * d * ef;
}

__device__ __forceinline__ float block_reduce(float acc) {
    // wave-64 shuffle reduction
    #pragma unroll
    for (int off = 32; off > 0; off >>= 1)
        acc += __shfl_down(acc, off, 64);
    __shared__ float wsum[NTHREADS / 64];
    int lane = threadIdx.x & 63;
    int wave = threadIdx.x >> 6;
    if (lane == 0) wsum[wave] = acc;
    __syncthreads();
    float s = 0.f;
    if (threadIdx.x == 0) {
        #pragma unroll
        for (int w = 0; w < NTHREADS / 64; ++w) s += wsum[w];
    }
    return s;  // valid on thread 0 only
}

__global__ __launch_bounds__(NTHREADS) void ef_loss_partial(
    const float* __restrict__ out, const float* __restrict__ tgt,
    float* __restrict__ partials, int n) {
    const int idx    = blockIdx.x * blockDim.x + threadIdx.x;
    const int stride = gridDim.x * blockDim.x;
    const int n4     = n >> 2;

    const float4* __restrict__ o4 = (const float4*)out;
    const float4* __restrict__ t4 = (const float4*)tgt;

    float acc = 0.f;
    for (int i = idx; i < n4; i += stride) {
        float4 o = o4[i];
        float4 t = t4[i];
        acc += ef_term(o.x, t.x);
        acc += ef_term(o.y, t.y);
        acc += ef_term(o.z, t.z);
        acc += ef_term(o.w, t.w);
    }
    // scalar tail (n not multiple of 4 — not hit for this shape, kept for safety)
    for (int i = (n4 << 2) + idx; i < n; i += stride)
        acc += ef_term(out[i], tgt[i]);

    float s = block_reduce(acc);
    if (threadIdx.x == 0) partials[blockIdx.x] = s;
}

__global__ __launch_bounds__(NTHREADS) void ef_loss_finalize(
    const float* __restrict__ partials, float* __restrict__ result,
    int nblocks, float inv_n) {
    float acc = 0.f;
    for (int i = threadIdx.x; i < nblocks; i += blockDim.x)
        acc += partials[i];
    float s = block_reduce(acc);
    if (threadIdx.x == 0) result[0] = s * inv_n;
}

extern "C" void kernel_launch(void* const* d_in, const int* in_sizes, int n_in,
                              void* d_out, int out_size, void* d_ws, size_t ws_size,
                              hipStream_t stream) {
    const float* out_p = (const float*)d_in[0];   // "output"
    const float* tgt_p = (const float*)d_in[1];   // "target"
    float* partials = (float*)d_ws;               // NBLOCKS floats = 8 KB
    float* result   = (float*)d_out;
    const int n = in_sizes[0];

    ef_loss_partial<<<NBLOCKS, NTHREADS, 0, stream>>>(out_p, tgt_p, partials, n);
    ef_loss_finalize<<<1, NTHREADS, 0, stream>>>(partials, result, NBLOCKS,
                                                 1.0f / (float)n);
}

// Round 2
// 145.797 us; speedup vs baseline: 1.0154x; 1.0154x over previous
//
#include <hip/hip_runtime.h>

// Loss = mean(0.5*(o-t)^2 * ef(t)) over N = 64*1*512*512 = 2^24 fp32 elements.
// ef(t) = BETA - exp((A-1)*ln(x) - x + BIAS),  x = (t - LOC)/SCALE  (see R0 notes)
// R1 analysis: grid-stride loop was latency-bound (2 loads in flight/wave,
// vmcnt(0) each iter). Fix: full unroll, 16 loads issued before compute.

#define NBLOCKS 2048
#define NTHREADS 256
#define F4_PER_THREAD 8   // 2048*256*8*4 = 2^24 elements exactly

__device__ __forceinline__ float ef_term(float o, float y) {
    constexpr float A_M1      = -0.93555708575356741f;  // EST_A - 1
    constexpr float NEG_LOC   =  1.1328205299926424e-27f;
    constexpr float INV_SCALE =  0.65034886603218541f;  // 1/1.5376362609160314
    constexpr float BIAS      = -56.8416699f;
    constexpr float BETA      =  5.0f;

    float x  = (y + NEG_LOC) * INV_SCALE;           // > 0 for y >= 0
    float ex = __expf(fmaf(A_M1, __logf(x), BIAS - x));
    float ef = BETA - ex;                            // == c when y == 0
    float d  = o - y;
    return 0.5f * d * d * ef;
}

__device__ __forceinline__ float block_reduce(float acc) {
    #pragma unroll
    for (int off = 32; off > 0; off >>= 1)
        acc += __shfl_down(acc, off, 64);
    __shared__ float wsum[NTHREADS / 64];
    int lane = threadIdx.x & 63;
    int wave = threadIdx.x >> 6;
    if (lane == 0) wsum[wave] = acc;
    __syncthreads();
    float s = 0.f;
    if (threadIdx.x == 0) {
        #pragma unroll
        for (int w = 0; w < NTHREADS / 64; ++w) s += wsum[w];
    }
    return s;  // valid on thread 0 only
}

// Fast path: n == NBLOCKS*NTHREADS*F4_PER_THREAD*4 exactly.
// Block b owns a contiguous chunk of NTHREADS*F4_PER_THREAD float4s;
// round r is fully coalesced: index = chunk + r*NTHREADS + tid.
__global__ __launch_bounds__(NTHREADS) void ef_loss_partial_fast(
    const float* __restrict__ out, const float* __restrict__ tgt,
    float* __restrict__ partials) {
    const int base = blockIdx.x * (NTHREADS * F4_PER_THREAD) + threadIdx.x;
    const float4* __restrict__ o4 = (const float4*)out;
    const float4* __restrict__ t4 = (const float4*)tgt;

    float4 o[F4_PER_THREAD], t[F4_PER_THREAD];
    // Issue ALL loads first — 16 dwordx4 in flight per lane before any wait.
    #pragma unroll
    for (int r = 0; r < F4_PER_THREAD; ++r) o[r] = o4[base + r * NTHREADS];
    #pragma unroll
    for (int r = 0; r < F4_PER_THREAD; ++r) t[r] = t4[base + r * NTHREADS];

    float a0 = 0.f, a1 = 0.f, a2 = 0.f, a3 = 0.f;
    #pragma unroll
    for (int r = 0; r < F4_PER_THREAD; ++r) {
        a0 += ef_term(o[r].x, t[r].x);
        a1 += ef_term(o[r].y, t[r].y);
        a2 += ef_term(o[r].z, t[r].z);
        a3 += ef_term(o[r].w, t[r].w);
    }
    float s = block_reduce((a0 + a1) + (a2 + a3));
    if (threadIdx.x == 0) partials[blockIdx.x] = s;
}

// Generic fallback (any n) — same as R1 kernel.
__global__ __launch_bounds__(NTHREADS) void ef_loss_partial_gen(
    const float* __restrict__ out, const float* __restrict__ tgt,
    float* __restrict__ partials, int n) {
    const int idx    = blockIdx.x * blockDim.x + threadIdx.x;
    const int stride = gridDim.x * blockDim.x;
    const int n4     = n >> 2;
    const float4* __restrict__ o4 = (const float4*)out;
    const float4* __restrict__ t4 = (const float4*)tgt;

    float acc = 0.f;
    for (int i = idx; i < n4; i += stride) {
        float4 o = o4[i];
        float4 t = t4[i];
        acc += ef_term(o.x, t.x);
        acc += ef_term(o.y, t.y);
        acc += ef_term(o.z, t.z);
        acc += ef_term(o.w, t.w);
    }
    for (int i = (n4 << 2) + idx; i < n; i += stride)
        acc += ef_term(out[i], tgt[i]);

    float s = block_reduce(acc);
    if (threadIdx.x == 0) partials[blockIdx.x] = s;
}

__global__ __launch_bounds__(NTHREADS) void ef_loss_finalize(
    const float* __restrict__ partials, float* __restrict__ result,
    int nblocks, float inv_n) {
    float acc = 0.f;
    for (int i = threadIdx.x; i < nblocks; i += blockDim.x)
        acc += partials[i];
    float s = block_reduce(acc);
    if (threadIdx.x == 0) result[0] = s * inv_n;
}

extern "C" void kernel_launch(void* const* d_in, const int* in_sizes, int n_in,
                              void* d_out, int out_size, void* d_ws, size_t ws_size,
                              hipStream_t stream) {
    const float* out_p = (const float*)d_in[0];   // "output"
    const float* tgt_p = (const float*)d_in[1];   // "target"
    float* partials = (float*)d_ws;               // NBLOCKS floats = 8 KB
    float* result   = (float*)d_out;
    const int n = in_sizes[0];

    if (n == NBLOCKS * NTHREADS * F4_PER_THREAD * 4) {
        ef_loss_partial_fast<<<NBLOCKS, NTHREADS, 0, stream>>>(out_p, tgt_p, partials);
    } else {
        ef_loss_partial_gen<<<NBLOCKS, NTHREADS, 0, stream>>>(out_p, tgt_p, partials, n);
    }
    ef_loss_finalize<<<1, NTHREADS, 0, stream>>>(partials, result, NBLOCKS,
                                                 1.0f / (float)n);
}

// Round 4
// 144.861 us; speedup vs baseline: 1.0220x; 1.0065x over previous
//
#include <hip/hip_runtime.h>

// Loss = mean(0.5*(o-t)^2 * ef(t)) over N = 64*1*512*512 = 2^24 fp32 elements.
// ef(t) = BETA - exp((A-1)*ln(x) - x + BIAS),  x = (t - LOC)/SCALE  (see R0 notes)
// R2: compiler collapsed the unroll to VGPR=32 (<=4 loads in flight) -> 44us.
// R3: tied "+v"(float4) waitcnt asm doesn't compile ("tied indirect").
// R4: asm loads + templated waitcnt that RETURNS an opaque zero g; every
// consumed value is OR'd with g (bit-exact) -> data dep pins use-after-wait.

#define NBLOCKS 2048
#define NTHREADS 256
#define F4_PER_THREAD 8   // 2048*256*8*4 = 2^24 elements exactly

__device__ __forceinline__ float ef_term(float o, float y) {
    constexpr float A_M1      = -0.93555708575356741f;  // EST_A - 1
    constexpr float NEG_LOC   =  1.1328205299926424e-27f;
    constexpr float INV_SCALE =  0.65034886603218541f;  // 1/1.5376362609160314
    constexpr float BIAS      = -56.8416699f;
    constexpr float BETA      =  5.0f;

    float x  = (y + NEG_LOC) * INV_SCALE;           // > 0 for y >= 0
    float ex = __expf(fmaf(A_M1, __logf(x), BIAS - x));
    float ef = BETA - ex;                            // == c when y == 0
    float d  = o - y;
    return 0.5f * d * d * ef;
}

// s_waitcnt vmcnt(N), then materialize an opaque 0 in a VGPR. Consumers OR
// their bits with the result -> cannot be hoisted above the wait.
template <int N>
__device__ __forceinline__ unsigned waitcnt_vm_zero() {
    unsigned g;
    asm volatile("s_waitcnt vmcnt(%1)\n\tv_mov_b32 %0, 0"
                 : "=v"(g) : "n"(N) : "memory");
    return g;
}

__device__ __forceinline__ float guard(float v, unsigned g) {
    return __uint_as_float(__float_as_uint(v) | g);
}

__device__ __forceinline__ float block_reduce(float acc) {
    #pragma unroll
    for (int off = 32; off > 0; off >>= 1)
        acc += __shfl_down(acc, off, 64);
    __shared__ float wsum[NTHREADS / 64];
    int lane = threadIdx.x & 63;
    int wave = threadIdx.x >> 6;
    if (lane == 0) wsum[wave] = acc;
    __syncthreads();
    float s = 0.f;
    if (threadIdx.x == 0) {
        #pragma unroll
        for (int w = 0; w < NTHREADS / 64; ++w) s += wsum[w];
    }
    return s;  // valid on thread 0 only
}

// Fast path: n == NBLOCKS*NTHREADS*F4_PER_THREAD*4 exactly.
// 16 global_load_dwordx4 in flight per lane; stage r consumes after
// s_waitcnt vmcnt(14-2r).
__global__ __launch_bounds__(NTHREADS, 4) void ef_loss_partial_fast(
    const float* __restrict__ out, const float* __restrict__ tgt,
    float* __restrict__ partials) {
    const int base = blockIdx.x * (NTHREADS * F4_PER_THREAD) + threadIdx.x;
    const float4* __restrict__ o4 = (const float4*)out;
    const float4* __restrict__ t4 = (const float4*)tgt;

    float4 o[F4_PER_THREAD], t[F4_PER_THREAD];
    #pragma unroll
    for (int r = 0; r < F4_PER_THREAD; ++r) {
        const float4* po = o4 + base + r * NTHREADS;
        const float4* pt = t4 + base + r * NTHREADS;
        asm volatile("global_load_dwordx4 %0, %1, off" : "=v"(o[r]) : "v"(po));
        asm volatile("global_load_dwordx4 %0, %1, off" : "=v"(t[r]) : "v"(pt));
    }

    float a0 = 0.f, a1 = 0.f, a2 = 0.f, a3 = 0.f;

#define EF_ROUND(r)                                                         \
    do {                                                                    \
        unsigned g = waitcnt_vm_zero<14 - 2 * (r)>();                       \
        a0 += ef_term(guard(o[r].x, g), guard(t[r].x, g));                  \
        a1 += ef_term(guard(o[r].y, g), guard(t[r].y, g));                  \
        a2 += ef_term(guard(o[r].z, g), guard(t[r].z, g));                  \
        a3 += ef_term(guard(o[r].w, g), guard(t[r].w, g));                  \
    } while (0)

    EF_ROUND(0); EF_ROUND(1); EF_ROUND(2); EF_ROUND(3);
    EF_ROUND(4); EF_ROUND(5); EF_ROUND(6); EF_ROUND(7);
#undef EF_ROUND

    float s = block_reduce((a0 + a1) + (a2 + a3));
    if (threadIdx.x == 0) partials[blockIdx.x] = s;
}

// Generic fallback (any n).
__global__ __launch_bounds__(NTHREADS) void ef_loss_partial_gen(
    const float* __restrict__ out, const float* __restrict__ tgt,
    float* __restrict__ partials, int n) {
    const int idx    = blockIdx.x * blockDim.x + threadIdx.x;
    const int stride = gridDim.x * blockDim.x;
    const int n4     = n >> 2;
    const float4* __restrict__ o4 = (const float4*)out;
    const float4* __restrict__ t4 = (const float4*)tgt;

    float acc = 0.f;
    for (int i = idx; i < n4; i += stride) {
        float4 o = o4[i];
        float4 t = t4[i];
        acc += ef_term(o.x, t.x);
        acc += ef_term(o.y, t.y);
        acc += ef_term(o.z, t.z);
        acc += ef_term(o.w, t.w);
    }
    for (int i = (n4 << 2) + idx; i < n; i += stride)
        acc += ef_term(out[i], tgt[i]);

    float s = block_reduce(acc);
    if (threadIdx.x == 0) partials[blockIdx.x] = s;
}

__global__ __launch_bounds__(NTHREADS) void ef_loss_finalize(
    const float* __restrict__ partials, float* __restrict__ result,
    int nblocks, float inv_n) {
    float acc = 0.f;
    for (int i = threadIdx.x; i < nblocks; i += blockDim.x)
        acc += partials[i];
    float s = block_reduce(acc);
    if (threadIdx.x == 0) result[0] = s * inv_n;
}

extern "C" void kernel_launch(void* const* d_in, const int* in_sizes, int n_in,
                              void* d_out, int out_size, void* d_ws, size_t ws_size,
                              hipStream_t stream) {
    const float* out_p = (const float*)d_in[0];   // "output"
    const float* tgt_p = (const float*)d_in[1];   // "target"
    float* partials = (float*)d_ws;               // NBLOCKS floats = 8 KB
    float* result   = (float*)d_out;
    const int n = in_sizes[0];

    if (n == NBLOCKS * NTHREADS * F4_PER_THREAD * 4) {
        ef_loss_partial_fast<<<NBLOCKS, NTHREADS, 0, stream>>>(out_p, tgt_p, partials);
    } else {
        ef_loss_partial_gen<<<NBLOCKS, NTHREADS, 0, stream>>>(out_p, tgt_p, partials, n);
    }
    ef_loss_finalize<<<1, NTHREADS, 0, stream>>>(partials, result, NBLOCKS,
                                                 1.0f / (float)n);
}